// Round 14
// baseline (151.829 us; speedup 1.0000x reference)
//
#include <hip/hip_runtime.h>
#include <stdint.h>

#define NNODE  1000
#define KSP    200
#define DIM    64
#define BATCH  8
#define NPB    8                        // nodes per block == waves per block
#define NBLK   (BATCH * NNODE / NPB)    // 1000 blocks
#define NCHUNK 16                       // 16 chunks x 64 = 1024 >= 1000

__global__ __launch_bounds__(512) void knn_edge_kernel(
    const float* __restrict__ locs,   // [B, N, 2]
    const float* __restrict__ emb,    // [B, N, 64]
    const float* __restrict__ W,      // [64]
    const float* __restrict__ bias,   // [64]
    float* __restrict__ out)
{
    __shared__ float4         sloc4[NNODE / 2];   // 8000 B
    __shared__ int            hist[NPB][256];     // 8192 B (counts -> starts -> cursors)
    __shared__ float          dS[NPB][256];       // 8192 B candidate d
    __shared__ unsigned short iS[NPB][256];       // 4096 B candidate local idx
    __shared__ float          stD[NPB][KSP];      // 6400 B sorted d (self removed)
    __shared__ unsigned short stI[NPB][KSP];      // 3200 B sorted idx
    __shared__ int            done1[NPB], done2[NPB], sB[NPB];

    const int tid   = threadIdx.x;
    const int wv    = tid >> 6;
    const int lane  = tid & 63;
    const int node0 = blockIdx.x * NPB;
    const int b     = node0 / NNODE;              // uniform per block (8 | 1000)
    const int ibase = node0 - b * NNODE;

    // ---- init LDS ----
    ((int4*)hist)[tid] = make_int4(0, 0, 0, 0);   // 512*4 = 2048 ints
    if (tid < NPB) { done1[tid] = 0; done2[tid] = 0; sB[tid] = -1; }
    if (tid < NNODE / 2)
        sloc4[tid] = ((const float4*)(locs + (size_t)b * NNODE * 2))[tid];
    __syncthreads();

    const float2* sloc = (const float2*)sloc4;

    // ---- output pointers ----
    const size_t E = (size_t)BATCH * NNODE * KSP;
    float* x_out = out;
    float* ei0   = out + (size_t)BATCH * NNODE * DIM;
    float* ei1   = ei0 + E;
    float* eemb  = ei1 + E;

    // ---- per-lane W/bias; early independent stores (x, ei0) for own node ----
    const int c4 = (lane & 15) << 2;
    const float4 w4 = *(const float4*)(W + c4);
    const float4 b4 = *(const float4*)(bias + c4);

    {
        const int mynode = node0 + wv;
        x_out[(size_t)mynode * DIM + lane] = emb[(size_t)mynode * DIM + lane];
        const size_t eb = (size_t)mynode * KSP;
        const float fn = (float)mynode;
        for (int t = lane; t < KSP; t += 64) ei0[eb + t] = fn;
    }

    // ---- node loop: 7-wave cooperative select, rotating storekeeper ----
    for (int k = 0; k < NPB; ++k) {
        const int excused = (k + NPB - 1) & 7;    // previous storekeeper
        if (wv == excused) continue;              // storing / catching up

        const int i_k = ibase + k;
        const float2 self = sloc[i_k];
        const int tIdx = (wv - k) & 7;            // 0..6 for team members

        // -- pass 1: histogram (7-way fixed chunk split) --
        #pragma unroll
        for (int cs = 0; cs < 3; ++cs) {
            int c = cs * 7 + tIdx;
            if (c < NCHUNK) {
                int j = c * 64 + lane;
                if (j < NNODE) {
                    float2 pt = sloc[j];
                    float dx = __fsub_rn(self.x, pt.x);
                    float dy = __fsub_rn(self.y, pt.y);
                    float d  = __fsqrt_rn(__fadd_rn(__fmul_rn(dx, dx), __fmul_rn(dy, dy)));
                    int q = (int)(d * 180.0f);    // <= 254 structurally
                    atomicAdd(&hist[k][q], 1);
                }
            }
        }
        if (lane == 0)
            __hip_atomic_fetch_add(&done1[k], 1, __ATOMIC_RELEASE, __HIP_MEMORY_SCOPE_WORKGROUP);

        // -- scan by designated wave (k+1)&7; others wait on sB --
        if (wv == ((k + 1) & 7)) {
            while (__hip_atomic_load(&done1[k], __ATOMIC_ACQUIRE, __HIP_MEMORY_SCOPE_WORKGROUP) < 7)
                __builtin_amdgcn_s_sleep(1);
            int4 h4 = ((int4*)&hist[k][0])[lane];
            int s0 = h4.x, s1 = s0 + h4.y, s2 = s1 + h4.z, s3 = s2 + h4.w;
            int sc = s3;
            #pragma unroll
            for (int off = 1; off < 64; off <<= 1) {
                int y = __shfl_up(sc, off, 64);
                if (lane >= off) sc += y;
            }
            int excl = sc - s3;
            int bc = 1 << 30;
            if      (excl + s0 >= KSP + 1) bc = 4 * lane;
            else if (excl + s1 >= KSP + 1) bc = 4 * lane + 1;
            else if (excl + s2 >= KSP + 1) bc = 4 * lane + 2;
            else if (excl + s3 >= KSP + 1) bc = 4 * lane + 3;
            #pragma unroll
            for (int off = 32; off; off >>= 1) bc = min(bc, __shfl_xor(bc, off, 64));
            int4 st;
            st.x = excl; st.y = excl + s0; st.z = excl + s1; st.w = excl + s2;
            ((int4*)&hist[k][0])[lane] = st;      // exclusive starts (= pass2 cursors)
            __builtin_amdgcn_wave_barrier();
            if (lane == 0)
                __hip_atomic_store(&sB[k], bc, __ATOMIC_RELEASE, __HIP_MEMORY_SCOPE_WORKGROUP);
        }
        int Bk;
        while ((Bk = __hip_atomic_load(&sB[k], __ATOMIC_ACQUIRE, __HIP_MEMORY_SCOPE_WORKGROUP)) < 0)
            __builtin_amdgcn_s_sleep(1);

        // -- pass 2: counting-sort placement (same 7-way split) --
        #pragma unroll
        for (int cs = 0; cs < 3; ++cs) {
            int c = cs * 7 + tIdx;
            if (c < NCHUNK) {
                int j = c * 64 + lane;
                if (j < NNODE) {
                    float2 pt = sloc[j];
                    float dx = __fsub_rn(self.x, pt.x);
                    float dy = __fsub_rn(self.y, pt.y);
                    float d  = __fsqrt_rn(__fadd_rn(__fmul_rn(dx, dx), __fmul_rn(dy, dy)));
                    int q = (int)(d * 180.0f);
                    if (q <= Bk) {
                        int slot = atomicAdd(&hist[k][q], 1);
                        if (slot < 256) { dS[k][slot] = d; iS[k][slot] = (unsigned short)j; }
                    }
                }
            }
        }
        if (lane == 0)
            __hip_atomic_fetch_add(&done2[k], 1, __ATOMIC_RELEASE, __HIP_MEMORY_SCOPE_WORKGROUP);

        // -- storekeeper (wave k): rank, permute to stash, stream stores --
        if (wv == k) {
            while (__hip_atomic_load(&done2[k], __ATOMIC_ACQUIRE, __HIP_MEMORY_SCOPE_WORKGROUP) < 7)
                __builtin_amdgcn_s_sleep(1);

            const int cumB = min(hist[k][Bk], 256);
            float myd[4]; int myidx[4]; int myr[4];
            int selfr = 0x7fffffff;
            #pragma unroll
            for (int s = 0; s < 4; ++s) {
                int t = lane + s * 64;
                myr[s] = KSP + 1;
                if (t < cumB) {
                    float d = dS[k][t];
                    int idx = iS[k][t];
                    int q = (int)(d * 180.0f);
                    int start = q ? hist[k][q - 1] : 0;
                    int end   = min(hist[k][q], 256);
                    int r = start;
                    for (int m = start; m < end; ++m) {
                        float dm = dS[k][m]; int im = iS[k][m];
                        r += (dm < d || (dm == d && im < idx)) ? 1 : 0;
                    }
                    myd[s] = d; myidx[s] = idx; myr[s] = r;
                    if (idx == i_k) selfr = r;
                }
            }
            #pragma unroll
            for (int off = 32; off; off >>= 1) selfr = min(selfr, __shfl_xor(selfr, off, 64));
            const int sp = selfr;
            #pragma unroll
            for (int s = 0; s < 4; ++s) {
                int r = myr[s];
                if (r <= KSP && r != sp) {
                    int tt = r - (r > sp ? 1 : 0);
                    if (tt < KSP) { stD[k][tt] = myd[s]; stI[k][tt] = (unsigned short)myidx[s]; }
                }
            }
            __builtin_amdgcn_wave_barrier();

            const size_t eb = (size_t)(node0 + k) * KSP;
            for (int t = lane; t < KSP; t += 64)
                ei1[eb + t] = (float)(b * NNODE + (int)stI[k][t]);

            float4* em4 = (float4*)(eemb + eb * DIM);
            for (int t = lane; t < KSP * (DIM / 4); t += 64) {
                int e = t >> 4;
                float d = stD[k][e];
                float4 v;
                v.x = fmaf(d, w4.x, b4.x);
                v.y = fmaf(d, w4.y, b4.y);
                v.z = fmaf(d, w4.z, b4.z);
                v.w = fmaf(d, w4.w, b4.w);
                em4[t] = v;
            }
        }
    }
}

extern "C" void kernel_launch(void* const* d_in, const int* in_sizes, int n_in,
                              void* d_out, int out_size, void* d_ws, size_t ws_size,
                              hipStream_t stream) {
    const float* locs = (const float*)d_in[0];
    const float* emb  = (const float*)d_in[1];
    const float* W    = (const float*)d_in[2];
    const float* bias = (const float*)d_in[3];
    float* out = (float*)d_out;

    knn_edge_kernel<<<NBLK, 512, 0, stream>>>(locs, emb, W, bias, out);
}

// Round 15
// 94.679 us; speedup vs baseline: 1.6036x; 1.6036x over previous
//
#include <hip/hip_runtime.h>
#include <stdint.h>

#define NNODE 1000
#define KSP   200
#define DIM   64
#define BATCH 8
#define WPB   8                          // waves (nodes) per block, 512 threads
#define NBLK  (BATCH * NNODE / WPB)      // 1000 blocks

__global__ __launch_bounds__(512) void knn_edge_kernel(
    const float* __restrict__ locs,   // [B, N, 2]
    const float* __restrict__ emb,    // [B, N, 64]
    const float* __restrict__ W,      // [64]
    const float* __restrict__ bias,   // [64]
    float* __restrict__ out)
{
    __shared__ float4         sloc4[NNODE / 2];   // 8000 B
    __shared__ int            hist[WPB][256];     // 8192 B (counts -> starts -> cursors/ends)
    __shared__ float          dS[WPB][256];       // 8192 B candidate distances
    __shared__ unsigned short iS[WPB][256];       // 4096 B candidate local indices

    const int tid  = threadIdx.x;
    const int w    = tid >> 6;
    const int lane = tid & 63;
    const int node = blockIdx.x * WPB + w;   // 0 .. 7999
    const int b    = node / NNODE;           // uniform across block (8 | 1000)
    const int i    = node - b * NNODE;

    // ---- stage batch locs (500 float4) + zero hist ----
    if (tid < NNODE / 2) sloc4[tid] = ((const float4*)(locs + (size_t)b * NNODE * 2))[tid];
    ((int4*)hist)[tid] = make_int4(0, 0, 0, 0);        // 512*int4 = 2048 ints exact
    __syncthreads();

    const float2 self = ((const float2*)sloc4)[i];

    // ---- early VMEM: x row copy + ei0 fill (drain under select) ----
    const size_t E = (size_t)BATCH * NNODE * KSP;
    float* x_out = out;
    float* ei0   = out + (size_t)BATCH * NNODE * DIM;
    float* ei1   = ei0 + E;
    float* eemb  = ei1 + E;

    const int c4 = (lane & 15) << 2;
    const float4 w4 = *(const float4*)(W + c4);
    const float4 b4 = *(const float4*)(bias + c4);

    x_out[(size_t)node * DIM + lane] = emb[(size_t)node * DIM + lane];
    const size_t ebase = (size_t)node * KSP;
    const float fnode = (float)node;
    for (int t = lane; t < KSP; t += 64) ei0[ebase + t] = fnode;

    // ---- pass 1: distances (exact XLA rounding), paired float4 reads, histogram ----
    #pragma unroll
    for (int s = 0; s < 8; ++s) {
        int i4 = s * 64 + lane;
        if (i4 < NNODE / 2) {
            float4 pp = sloc4[i4];                     // points 2*i4, 2*i4+1
            float dxa = __fsub_rn(self.x, pp.x);
            float dya = __fsub_rn(self.y, pp.y);
            float da  = __fsqrt_rn(__fadd_rn(__fmul_rn(dxa, dxa), __fmul_rn(dya, dya)));
            float dxb = __fsub_rn(self.x, pp.z);
            float dyb = __fsub_rn(self.y, pp.w);
            float db  = __fsqrt_rn(__fadd_rn(__fmul_rn(dxb, dxb), __fmul_rn(dyb, dyb)));
            atomicAdd(&hist[w][(int)(da * 180.0f)], 1);   // q <= 254 structurally
            atomicAdd(&hist[w][(int)(db * 180.0f)], 1);
        }
    }
    __builtin_amdgcn_wave_barrier();

    // ---- lane-transposed scan: lane l owns bins 4l..4l+3 ----
    int4 h4 = ((int4*)&hist[w][0])[lane];
    int s0 = h4.x;
    int s1 = s0 + h4.y;
    int s2 = s1 + h4.z;
    int s3 = s2 + h4.w;
    int sc = s3;
    #pragma unroll
    for (int off = 1; off < 64; off <<= 1) {
        int y = __shfl_up(sc, off, 64);
        if (lane >= off) sc += y;
    }
    const int excl = sc - s3;
    int bc = 1 << 30;
    if      (excl + s0 >= KSP + 1) bc = 4 * lane;
    else if (excl + s1 >= KSP + 1) bc = 4 * lane + 1;
    else if (excl + s2 >= KSP + 1) bc = 4 * lane + 2;
    else if (excl + s3 >= KSP + 1) bc = 4 * lane + 3;
    #pragma unroll
    for (int off = 32; off; off >>= 1) bc = min(bc, __shfl_xor(bc, off, 64));
    const int B = bc;
    int4 st;
    st.x = excl; st.y = excl + s0; st.z = excl + s1; st.w = excl + s2;
    ((int4*)&hist[w][0])[lane] = st;                   // exclusive starts = pass2 cursors
    __builtin_amdgcn_wave_barrier();

    // ---- pass 2: counting-sort placement (recompute d; LDS-only) ----
    #pragma unroll
    for (int s = 0; s < 8; ++s) {
        int i4 = s * 64 + lane;
        if (i4 < NNODE / 2) {
            float4 pp = sloc4[i4];
            float dxa = __fsub_rn(self.x, pp.x);
            float dya = __fsub_rn(self.y, pp.y);
            float da  = __fsqrt_rn(__fadd_rn(__fmul_rn(dxa, dxa), __fmul_rn(dya, dya)));
            int qa = (int)(da * 180.0f);
            if (qa <= B) {
                int slot = atomicAdd(&hist[w][qa], 1);
                if (slot < 256) { dS[w][slot] = da; iS[w][slot] = (unsigned short)(2 * i4); }
            }
            float dxb = __fsub_rn(self.x, pp.z);
            float dyb = __fsub_rn(self.y, pp.w);
            float db  = __fsqrt_rn(__fadd_rn(__fmul_rn(dxb, dxb), __fmul_rn(dyb, dyb)));
            int qb = (int)(db * 180.0f);
            if (qb <= B) {
                int slot = atomicAdd(&hist[w][qb], 1);
                if (slot < 256) { dS[w][slot] = db; iS[w][slot] = (unsigned short)(2 * i4 + 1); }
            }
        }
    }
    __builtin_amdgcn_wave_barrier();
    // hist[q] = inclusive bin end for q <= B

    const int cumB = min(hist[w][B], 256);

    // ---- exact rank: bin start + count of (d,idx)-smaller within bin ----
    float myd[4]; int myidx[4]; int myr[4];
    int selfr = 0x7fffffff;
    #pragma unroll
    for (int s = 0; s < 4; ++s) {
        int t = lane + s * 64;
        myr[s] = KSP + 1;
        if (t < cumB) {
            float d  = dS[w][t];
            int  idx = iS[w][t];
            int  q   = (int)(d * 180.0f);
            int start = q ? hist[w][q - 1] : 0;
            int end   = min(hist[w][q], 256);
            int r = start;
            for (int m = start; m < end; ++m) {
                float dm = dS[w][m];
                r += (dm < d) ? 1 : 0;
                if (dm == d) r += (iS[w][m] < (unsigned short)idx) ? 1 : 0;  // rare ties
            }
            myd[s] = d; myidx[s] = idx; myr[s] = r;
            if (idx == i) selfr = r;
        }
    }
    #pragma unroll
    for (int off = 32; off; off >>= 1) selfr = min(selfr, __shfl_xor(selfr, off, 64));
    const int sp = selfr;
    __builtin_amdgcn_wave_barrier();                   // all rank reads before permute writes

    // ---- in-place permute (rank <= 200, self included at sp) ----
    #pragma unroll
    for (int s = 0; s < 4; ++s) {
        int t = lane + s * 64;
        if (t < cumB) {
            int r = myr[s];
            if (r <= KSP) { dS[w][r] = myd[s]; iS[w][r] = (unsigned short)myidx[s]; }
        }
    }
    __builtin_amdgcn_wave_barrier();

    // ---- dependent stores: ei1, eemb (skip self via slot shift) ----
    for (int t = lane; t < KSP; t += 64) {
        int slot = t + (t >= sp ? 1 : 0);
        ei1[ebase + t] = (float)(b * NNODE + (int)iS[w][slot]);
    }

    float4* em4 = (float4*)(eemb + ebase * DIM);
    for (int t = lane; t < KSP * (DIM / 4); t += 64) {
        int e    = t >> 4;
        int slot = e + (e >= sp ? 1 : 0);
        float d = dS[w][slot];
        float4 v;
        v.x = fmaf(d, w4.x, b4.x);
        v.y = fmaf(d, w4.y, b4.y);
        v.z = fmaf(d, w4.z, b4.z);
        v.w = fmaf(d, w4.w, b4.w);
        em4[t] = v;
    }
}

extern "C" void kernel_launch(void* const* d_in, const int* in_sizes, int n_in,
                              void* d_out, int out_size, void* d_ws, size_t ws_size,
                              hipStream_t stream) {
    const float* locs = (const float*)d_in[0];
    const float* emb  = (const float*)d_in[1];
    const float* W    = (const float*)d_in[2];
    const float* bias = (const float*)d_in[3];
    float* out = (float*)d_out;

    knn_edge_kernel<<<NBLK, 512, 0, stream>>>(locs, emb, W, bias, out);
}